// Round 8
// baseline (295.000 us; speedup 1.0000x reference)
//
#include <hip/hip_runtime.h>

#define HIDDEN 16
#define CB 1024         // nodes per bucket/tile (power of two)
#define CB_SHIFT 10
#define NCB2_MAX 128    // max buckets for 2D path (n <= 131072)
#define NCB_MAX 512     // max buckets for split fallback
#define CHUNK 8192      // edges per block in hist/fill passes
#define SPL 8           // slice-blocks per bucket
#define BT 1024         // threads per sliced block

// ======================= shared helpers =======================

__global__ void k_zero(unsigned int* a, int na, unsigned int* b, int nb) {
    int i = blockIdx.x * blockDim.x + threadIdx.x;
    if (i < na) a[i] = 0u;
    else if (i < na + nb) b[i - na] = 0u;
}

__global__ void k_hist_c(const int* __restrict__ dst, int e, int ncb,
                         unsigned int* __restrict__ cntc) {
    __shared__ unsigned int h[NCB_MAX];
    for (int i = threadIdx.x; i < ncb; i += blockDim.x) h[i] = 0u;
    __syncthreads();
    int start = blockIdx.x * CHUNK;
    int end = min(start + CHUNK, e);
    int i = start + threadIdx.x;
    for (; i + 3 * 256 < end; i += 4 * 256) {
        unsigned d0 = dst[i], d1 = dst[i + 256], d2 = dst[i + 512], d3 = dst[i + 768];
        atomicAdd(&h[d0 >> CB_SHIFT], 1u);
        atomicAdd(&h[d1 >> CB_SHIFT], 1u);
        atomicAdd(&h[d2 >> CB_SHIFT], 1u);
        atomicAdd(&h[d3 >> CB_SHIFT], 1u);
    }
    for (; i < end; i += 256)
        atomicAdd(&h[((unsigned)dst[i]) >> CB_SHIFT], 1u);
    __syncthreads();
    for (int j = threadIdx.x; j < ncb; j += blockDim.x)
        if (h[j]) atomicAdd(&cntc[j], h[j]);
}

__global__ void k_scan(const unsigned int* __restrict__ cnt, int nb,
                       unsigned int* __restrict__ base,
                       unsigned int* __restrict__ cursor) {
    __shared__ unsigned int tsum[256];
    int t = threadIdx.x;
    int K = (nb + 255) / 256;
    unsigned int s = 0;
    for (int k = 0; k < K; k++) {
        int i = t * K + k;
        if (i < nb) s += cnt[i];
    }
    tsum[t] = s;
    __syncthreads();
    for (int off = 1; off < 256; off <<= 1) {
        unsigned int v = 0;
        if (t >= off) v = tsum[t - off];
        __syncthreads();
        if (t >= off) tsum[t] += v;
        __syncthreads();
    }
    unsigned int run = (t == 0) ? 0u : tsum[t - 1];
    for (int k = 0; k < K; k++) {
        int i = t * K + k;
        if (i < nb) { base[i] = run; cursor[i] = run; run += cnt[i]; }
    }
}

// records: (src << 10) | dst_local
__global__ void k_fill_c(const int* __restrict__ src, const int* __restrict__ dst,
                         int e, int ncb, unsigned int* cursorc,
                         unsigned int* __restrict__ tmp) {
    __shared__ unsigned int h[NCB_MAX];
    __shared__ unsigned int lbase[NCB_MAX];
    for (int i = threadIdx.x; i < ncb; i += blockDim.x) h[i] = 0u;
    __syncthreads();
    int start = blockIdx.x * CHUNK;
    int end = min(start + CHUNK, e);
    int i = start + threadIdx.x;
    for (; i + 3 * 256 < end; i += 4 * 256) {
        unsigned d0 = dst[i], d1 = dst[i + 256], d2 = dst[i + 512], d3 = dst[i + 768];
        atomicAdd(&h[d0 >> CB_SHIFT], 1u);
        atomicAdd(&h[d1 >> CB_SHIFT], 1u);
        atomicAdd(&h[d2 >> CB_SHIFT], 1u);
        atomicAdd(&h[d3 >> CB_SHIFT], 1u);
    }
    for (; i < end; i += 256)
        atomicAdd(&h[((unsigned)dst[i]) >> CB_SHIFT], 1u);
    __syncthreads();
    for (int j = threadIdx.x; j < ncb; j += blockDim.x) {
        unsigned int c = h[j];
        lbase[j] = c ? atomicAdd(&cursorc[j], c) : 0u;
        h[j] = 0u;
    }
    __syncthreads();
    for (i = start + threadIdx.x; i < end; i += 256) {
        unsigned int d = (unsigned)dst[i];
        unsigned int b = d >> CB_SHIFT;
        unsigned int r = atomicAdd(&h[b], 1u);
        tmp[lbase[b] + r] = (((unsigned)src[i]) << CB_SHIFT) | (d & (CB - 1u));
    }
}

// ======================= 2D-tiled path =======================

// degree partials: slice sl of bucket b -> degp[sl*n + node] (no global atomics)
__global__ __launch_bounds__(BT) void
k_deg_p(const unsigned int* __restrict__ tmp,
        const unsigned int* __restrict__ basec,
        const unsigned int* __restrict__ cntc,
        unsigned int* __restrict__ degp, int n) {
    __shared__ unsigned int degl[CB];
    int t = threadIdx.x;
    degl[t] = 0u;
    __syncthreads();
    int b = blockIdx.x / SPL, sl = blockIdx.x % SPL;
    unsigned int s = basec[b], m = cntc[b];
    for (unsigned int i = sl * BT + t; i < m; i += SPL * BT)
        atomicAdd(&degl[tmp[s + i] & (CB - 1u)], 1u);
    __syncthreads();
    int node = b * CB + t;
    if (node < n) degp[(size_t)sl * n + node] = degl[t];
}

// inv = rsqrt(1 + sum of partials); xs4 = {x*inv, inv}
__global__ void k_inv(const unsigned int* __restrict__ degp,
                      const float* __restrict__ x,
                      float4* __restrict__ xs4, int n) {
    int i = blockIdx.x * blockDim.x + threadIdx.x;
    if (i >= n) return;
    unsigned int d = 1u;
#pragma unroll
    for (int sl = 0; sl < SPL; sl++) d += degp[(size_t)sl * n + i];
    float iv = rsqrtf((float)d);
    xs4[i] = make_float4(x[3 * i] * iv, x[3 * i + 1] * iv, x[3 * i + 2] * iv, iv);
}

// 2nd-level hist: src-bucket counts per dst-bucket -> cnt2[b*ncb + sb]
__global__ __launch_bounds__(BT) void
k_hist2(const unsigned int* __restrict__ tmp,
        const unsigned int* __restrict__ basec,
        const unsigned int* __restrict__ cntc,
        unsigned int* __restrict__ cnt2, int ncb) {
    __shared__ unsigned int h2[NCB2_MAX];
    int t = threadIdx.x;
    if (t < ncb) h2[t] = 0u;
    __syncthreads();
    int b = blockIdx.x / SPL, sl = blockIdx.x % SPL;
    unsigned int s = basec[b], m = cntc[b];
    for (unsigned int i = sl * BT + t; i < m; i += SPL * BT)
        atomicAdd(&h2[tmp[s + i] >> (2 * CB_SHIFT)], 1u);
    __syncthreads();
    if (t < ncb && h2[t]) atomicAdd(&cnt2[b * ncb + t], h2[t]);
}

// 1024-thread scan over ncb^2 entries (+ sentinel)
__global__ __launch_bounds__(BT) void
k_scan2(const unsigned int* __restrict__ cnt, int nb,
        unsigned int* __restrict__ base, unsigned int* __restrict__ cursor) {
    __shared__ unsigned int tsum[BT];
    int t = threadIdx.x;
    int K = (nb + BT - 1) / BT;
    unsigned int s = 0;
    for (int k = 0; k < K; k++) {
        int i = t * K + k;
        if (i < nb) s += cnt[i];
    }
    tsum[t] = s;
    __syncthreads();
    for (int off = 1; off < BT; off <<= 1) {
        unsigned int v = 0;
        if (t >= off) v = tsum[t - off];
        __syncthreads();
        if (t >= off) tsum[t] += v;
        __syncthreads();
    }
    unsigned int run = (t == 0) ? 0u : tsum[t - 1];
    for (int k = 0; k < K; k++) {
        int i = t * K + k;
        if (i < nb) { base[i] = run; cursor[i] = run; run += cnt[i]; }
    }
    if (t == BT - 1) base[nb] = tsum[BT - 1];
}

// scatter records into (dstb, srcb)-sorted tmp2
__global__ __launch_bounds__(BT) void
k_fill2(const unsigned int* __restrict__ tmp,
        const unsigned int* __restrict__ basec,
        const unsigned int* __restrict__ cntc,
        unsigned int* cursor2, unsigned int* __restrict__ tmp2, int ncb) {
    __shared__ unsigned int h2[NCB2_MAX];
    __shared__ unsigned int lb[NCB2_MAX];
    int t = threadIdx.x;
    if (t < ncb) h2[t] = 0u;
    __syncthreads();
    int b = blockIdx.x / SPL, sl = blockIdx.x % SPL;
    unsigned int s = basec[b], m = cntc[b];
    for (unsigned int i = sl * BT + t; i < m; i += SPL * BT)
        atomicAdd(&h2[tmp[s + i] >> (2 * CB_SHIFT)], 1u);
    __syncthreads();
    if (t < ncb) {
        unsigned int c = h2[t];
        lb[t] = c ? atomicAdd(&cursor2[b * ncb + t], c) : 0u;
        h2[t] = 0u;
    }
    __syncthreads();
    for (unsigned int i = sl * BT + t; i < m; i += SPL * BT) {
        unsigned int rec = tmp[s + i];
        unsigned int sb = rec >> (2 * CB_SHIFT);
        unsigned int r = atomicAdd(&h2[sb], 1u);
        tmp2[lb[sb] + r] = rec;
    }
}

// layer-1 aggregate, 2D-tiled: stage 16KB xs4 src-tile in LDS, all per-edge
// accesses become LDS ops. Slice sl handles src-tiles sl, sl+SPL, ...
__global__ __launch_bounds__(BT) void
k_s1_2d(const unsigned int* __restrict__ tmp2,
        const unsigned int* __restrict__ base2,
        const float4* __restrict__ xs4,
        float* __restrict__ aggp, int n, int ncb) {
    __shared__ float4 tile[CB];                 // 16 KB
    __shared__ float a0[CB], a1[CB], a2[CB];    // 12 KB
    int t = threadIdx.x;
    a0[t] = 0.f; a1[t] = 0.f; a2[t] = 0.f;
    int b = blockIdx.x / SPL, sl = blockIdx.x % SPL;
    size_t bp = (size_t)b * ncb;
    for (int sb = sl; sb < ncb; sb += SPL) {
        unsigned int beg = base2[bp + sb], end = base2[bp + sb + 1];
        if (beg == end) continue;
        __syncthreads();                         // acc zeros / prev readers done
        int idx = (sb << CB_SHIFT) + t;
        tile[t] = xs4[idx < n ? idx : 0];        // coalesced 16 KB stage
        __syncthreads();
        for (unsigned int i = beg + t; i < end; i += BT) {
            unsigned int rec = tmp2[i];          // coalesced
            float4 v = tile[(rec >> CB_SHIFT) & (CB - 1u)];  // LDS gather
            unsigned int dl = rec & (CB - 1u);
            atomicAdd(&a0[dl], v.x);
            atomicAdd(&a1[dl], v.y);
            atomicAdd(&a2[dl], v.z);
        }
    }
    __syncthreads();
    int node = (b << CB_SHIFT) + t;
    if (node < n) {                              // plain coalesced partial stores
        aggp[(size_t)(sl * 3 + 0) * n + node] = a0[t];
        aggp[(size_t)(sl * 3 + 1) * n + node] = a1[t];
        aggp[(size_t)(sl * 3 + 2) * n + node] = a2[t];
    }
}

// epilogue: reduce partials, ×inv[dst], self-loop, W1+b1+relu+W2 -> t2s
__global__ void k_epi(const float* __restrict__ aggp, const float4* __restrict__ xs4,
                      const float* __restrict__ W1, const float* __restrict__ b1,
                      const float* __restrict__ W2,
                      float* __restrict__ t2s, int n) {
    int i = blockIdx.x * blockDim.x + threadIdx.x;
    if (i >= n) return;
    float4 xv = xs4[i];
    float iv = xv.w;
    float s0 = xv.x, s1 = xv.y, s2 = xv.z;      // self-loop terms (x*inv)
#pragma unroll
    for (int sl = 0; sl < SPL; sl++) {
        s0 += aggp[(size_t)(sl * 3 + 0) * n + i];
        s1 += aggp[(size_t)(sl * 3 + 1) * n + i];
        s2 += aggp[(size_t)(sl * 3 + 2) * n + i];
    }
    float v0 = iv * s0, v1 = iv * s1, v2 = iv * s2;
    float acc = 0.f;
#pragma unroll
    for (int j = 0; j < HIDDEN; j++) {
        float h = fmaxf(fmaf(v0, W1[j], fmaf(v1, W1[HIDDEN + j],
                       fmaf(v2, W1[2 * HIDDEN + j], b1[j]))), 0.f);
        acc += h * W2[j];
    }
    t2s[i] = acc * iv;                           // pre-scaled by inv
}

// layer-2 aggregate, 2D-tiled: 4KB t2s tile in LDS
__global__ __launch_bounds__(BT) void
k_s2_2d(const unsigned int* __restrict__ tmp2,
        const unsigned int* __restrict__ base2,
        const float* __restrict__ t2s,
        float* __restrict__ op, int n, int ncb) {
    __shared__ float tile[CB];
    __shared__ float o[CB];
    int t = threadIdx.x;
    o[t] = 0.f;
    int b = blockIdx.x / SPL, sl = blockIdx.x % SPL;
    size_t bp = (size_t)b * ncb;
    for (int sb = sl; sb < ncb; sb += SPL) {
        unsigned int beg = base2[bp + sb], end = base2[bp + sb + 1];
        if (beg == end) continue;
        __syncthreads();
        int idx = (sb << CB_SHIFT) + t;
        tile[t] = t2s[idx < n ? idx : 0];
        __syncthreads();
        for (unsigned int i = beg + t; i < end; i += BT) {
            unsigned int rec = tmp2[i];
            atomicAdd(&o[rec & (CB - 1u)], tile[(rec >> CB_SHIFT) & (CB - 1u)]);
        }
    }
    __syncthreads();
    int node = (b << CB_SHIFT) + t;
    if (node < n) op[(size_t)sl * n + node] = o[t];
}

// out = b2 + self-loop + inv[dst]*sum(partials)
__global__ void k_out(const float* __restrict__ op, const float* __restrict__ t2s,
                      const float4* __restrict__ xs4, const float* __restrict__ b2,
                      float* __restrict__ out, int n) {
    int i = blockIdx.x * blockDim.x + threadIdx.x;
    if (i >= n) return;
    float s = 0.f;
#pragma unroll
    for (int sl = 0; sl < SPL; sl++) s += op[(size_t)sl * n + i];
    float iv = xs4[i].w;
    out[i] = b2[0] + t2s[i] * iv + iv * s;
}

// ======================= split fallback (R7 path) =======================

__global__ __launch_bounds__(BT) void
k_deg_split(const unsigned int* __restrict__ tmp, const unsigned int* __restrict__ basec,
            const unsigned int* __restrict__ cntc, unsigned int* __restrict__ deg, int n) {
    __shared__ unsigned int degl[CB];
    int t = threadIdx.x;
    degl[t] = 0u;
    __syncthreads();
    int b = blockIdx.x / SPL, sl = blockIdx.x % SPL;
    unsigned int s = basec[b], m = cntc[b];
    for (unsigned int i = sl * BT + t; i < m; i += SPL * BT)
        atomicAdd(&degl[tmp[s + i] & (CB - 1u)], 1u);
    __syncthreads();
    int node = b * CB + t;
    unsigned int c = degl[t];
    if (node < n && c) atomicAdd(&deg[node], c);
}
__global__ void k_inv_s(const unsigned int* __restrict__ deg, const float* __restrict__ x,
                        float4* __restrict__ xs4, int n) {
    int i = blockIdx.x * blockDim.x + threadIdx.x;
    if (i >= n) return;
    float iv = rsqrtf((float)(deg[i] + 1u));
    xs4[i] = make_float4(x[3 * i] * iv, x[3 * i + 1] * iv, x[3 * i + 2] * iv, iv);
}
__global__ __launch_bounds__(BT) void
k_s1_split(const unsigned int* __restrict__ tmp, const unsigned int* __restrict__ basec,
           const unsigned int* __restrict__ cntc, const float4* __restrict__ xs4,
           float* __restrict__ agg0, float* __restrict__ agg1, float* __restrict__ agg2, int n) {
    __shared__ float a0[CB], a1[CB], a2[CB];
    int t = threadIdx.x;
    a0[t] = 0.f; a1[t] = 0.f; a2[t] = 0.f;
    __syncthreads();
    int b = blockIdx.x / SPL, sl = blockIdx.x % SPL;
    unsigned int s = basec[b], m = cntc[b];
    for (unsigned int i = sl * BT + t; i < m; i += SPL * BT) {
        unsigned rec = tmp[s + i];
        float4 v = xs4[rec >> CB_SHIFT];
        unsigned dl = rec & (CB - 1u);
        atomicAdd(&a0[dl], v.x); atomicAdd(&a1[dl], v.y); atomicAdd(&a2[dl], v.z);
    }
    __syncthreads();
    int node = b * CB + t;
    if (node < n) {
        if (a0[t] != 0.f) atomicAdd(&agg0[node], a0[t]);
        if (a1[t] != 0.f) atomicAdd(&agg1[node], a1[t]);
        if (a2[t] != 0.f) atomicAdd(&agg2[node], a2[t]);
    }
}
__global__ void k_epi_s(const float* __restrict__ agg0, const float* __restrict__ agg1,
                        const float* __restrict__ agg2, const float4* __restrict__ xs4,
                        const float* __restrict__ W1, const float* __restrict__ b1,
                        const float* __restrict__ W2, const float* __restrict__ b2,
                        float* __restrict__ t2s, float* __restrict__ out, int n) {
    int i = blockIdx.x * blockDim.x + threadIdx.x;
    if (i >= n) return;
    float4 xv = xs4[i];
    float iv = xv.w;
    float v0 = iv * (agg0[i] + xv.x), v1 = iv * (agg1[i] + xv.y), v2 = iv * (agg2[i] + xv.z);
    float acc = 0.f;
#pragma unroll
    for (int j = 0; j < HIDDEN; j++) {
        float h = fmaxf(fmaf(v0, W1[j], fmaf(v1, W1[HIDDEN + j],
                       fmaf(v2, W1[2 * HIDDEN + j], b1[j]))), 0.f);
        acc += h * W2[j];
    }
    t2s[i] = acc * iv;
    out[i] = b2[0] + acc * iv * iv;
}
__global__ __launch_bounds__(BT) void
k_s2_split(const unsigned int* __restrict__ tmp, const unsigned int* __restrict__ basec,
           const unsigned int* __restrict__ cntc, const float* __restrict__ t2s,
           const float4* __restrict__ xs4, float* __restrict__ out, int n) {
    __shared__ float o[CB];
    int t = threadIdx.x;
    o[t] = 0.f;
    __syncthreads();
    int b = blockIdx.x / SPL, sl = blockIdx.x % SPL;
    unsigned int s = basec[b], m = cntc[b];
    for (unsigned int i = sl * BT + t; i < m; i += SPL * BT) {
        unsigned rec = tmp[s + i];
        atomicAdd(&o[rec & (CB - 1u)], t2s[rec >> CB_SHIFT]);
    }
    __syncthreads();
    int node = b * CB + t;
    if (node < n && o[t] != 0.f) atomicAdd(&out[node], o[t] * xs4[node].w);
}

// ======================= launch =======================

extern "C" void kernel_launch(void* const* d_in, const int* in_sizes, int n_in,
                              void* d_out, int out_size, void* d_ws, size_t ws_size,
                              hipStream_t stream) {
    const float* x  = (const float*)d_in[0];
    const int*   ei = (const int*)d_in[1];
    const float* W1 = (const float*)d_in[2];
    const float* b1 = (const float*)d_in[3];
    const float* W2 = (const float*)d_in[4];
    const float* b2 = (const float*)d_in[5];
    float* out = (float*)d_out;

    int n = in_sizes[0] / 3;
    int e = in_sizes[1] / 2;
    const int* src = ei;
    const int* dst = ei + e;
    const int B = 256;

    int ncb = (n + CB - 1) / CB;
    int ncb2 = ncb * ncb;
    int gridE = (e + CHUNK - 1) / CHUNK;
    int gridN = (n + B - 1) / B;

    // 2D path workspace: xs4[n] | U[3*SPL*n] | t2s[n] | cntc/basec/cursorc[3*ncb]
    //                  | cnt2[ncb2] base2[ncb2+1] cursor2[ncb2] | tmp[e] tmp2[e]
    size_t need2d = (size_t)n * 16 + (size_t)(3 * SPL) * n * 4 + (size_t)n * 4
                  + (size_t)ncb * 12 + ((size_t)3 * ncb2 + 1) * 4 + (size_t)e * 8;
    size_t needsp = (size_t)n * 16 + (size_t)n * 16 + (size_t)n * 4
                  + (size_t)ncb * 12 + (size_t)e * 4;

    if (ncb <= NCB2_MAX && n < (1 << 22) && ws_size >= need2d) {
        float4* xs4 = (float4*)d_ws;                           // n
        float* U    = (float*)(xs4 + n);                       // 3*SPL*n (aliased)
        float* t2s  = U + (size_t)(3 * SPL) * n;               // n
        unsigned int* cntc    = (unsigned int*)(t2s + n);      // ncb
        unsigned int* basec   = cntc + ncb;
        unsigned int* cursorc = basec + ncb;
        unsigned int* cnt2    = cursorc + ncb;                 // ncb2
        unsigned int* base2   = cnt2 + ncb2;                   // ncb2+1
        unsigned int* cursor2 = base2 + ncb2 + 1;              // ncb2
        unsigned int* tmp     = cursor2 + ncb2;                // e
        unsigned int* tmp2    = tmp + e;                       // e
        unsigned int* degp = (unsigned int*)U;                 // alias: SPL*n
        float* aggp = U;                                       // alias: 3*SPL*n
        float* op   = U;                                       // alias: SPL*n

        k_zero<<<(ncb2 + ncb + B - 1) / B, B, 0, stream>>>(cnt2, ncb2, cntc, ncb);
        k_hist_c<<<gridE, B, 0, stream>>>(dst, e, ncb, cntc);
        k_scan<<<1, B, 0, stream>>>(cntc, ncb, basec, cursorc);
        k_fill_c<<<gridE, B, 0, stream>>>(src, dst, e, ncb, cursorc, tmp);
        k_deg_p<<<ncb * SPL, BT, 0, stream>>>(tmp, basec, cntc, degp, n);
        k_inv<<<gridN, B, 0, stream>>>(degp, x, xs4, n);
        k_hist2<<<ncb * SPL, BT, 0, stream>>>(tmp, basec, cntc, cnt2, ncb);
        k_scan2<<<1, BT, 0, stream>>>(cnt2, ncb2, base2, cursor2);
        k_fill2<<<ncb * SPL, BT, 0, stream>>>(tmp, basec, cntc, cursor2, tmp2, ncb);
        k_s1_2d<<<ncb * SPL, BT, 0, stream>>>(tmp2, base2, xs4, aggp, n, ncb);
        k_epi<<<gridN, B, 0, stream>>>(aggp, xs4, W1, b1, W2, t2s, n);
        k_s2_2d<<<ncb * SPL, BT, 0, stream>>>(tmp2, base2, t2s, op, n, ncb);
        k_out<<<gridN, B, 0, stream>>>(op, t2s, xs4, b2, out, n);
    } else if (ncb <= NCB_MAX && n < (1 << 22) && ws_size >= needsp) {
        float4* xs4 = (float4*)d_ws;
        float* agg0 = (float*)(xs4 + n);
        float* agg1 = agg0 + n;
        float* agg2 = agg1 + n;
        unsigned int* deg = (unsigned int*)(agg2 + n);
        float* t2s = (float*)(deg + n);
        unsigned int* cntc    = (unsigned int*)(t2s + n);
        unsigned int* basec   = cntc + ncb;
        unsigned int* cursorc = basec + ncb;
        unsigned int* tmp     = cursorc + ncb;

        k_zero<<<(4 * n + ncb + B - 1) / B, B, 0, stream>>>((unsigned int*)agg0, 4 * n, cntc, ncb);
        k_hist_c<<<gridE, B, 0, stream>>>(dst, e, ncb, cntc);
        k_scan<<<1, B, 0, stream>>>(cntc, ncb, basec, cursorc);
        k_fill_c<<<gridE, B, 0, stream>>>(src, dst, e, ncb, cursorc, tmp);
        k_deg_split<<<ncb * SPL, BT, 0, stream>>>(tmp, basec, cntc, deg, n);
        k_inv_s<<<gridN, B, 0, stream>>>(deg, x, xs4, n);
        k_s1_split<<<ncb * SPL, BT, 0, stream>>>(tmp, basec, cntc, xs4, agg0, agg1, agg2, n);
        k_epi_s<<<gridN, B, 0, stream>>>(agg0, agg1, agg2, xs4, W1, b1, W2, b2, t2s, out, n);
        k_s2_split<<<ncb * SPL, BT, 0, stream>>>(tmp, basec, cntc, t2s, xs4, out, n);
    }
}

// Round 9
// 213.050 us; speedup vs baseline: 1.3847x; 1.3847x over previous
//
#include <hip/hip_runtime.h>

#define HIDDEN 16
#define CB 1024         // nodes per coarse bucket (power of two)
#define CB_SHIFT 10
#define NCB_MAX 512     // max coarse buckets
#define CHUNK 8192      // edges per block in hist/fill passes
#define SPL 8           // slice-blocks per bucket in count/scatter kernels
#define BT 1024         // threads per sliced block

// ======================= sorted-CSR path =======================

__global__ void k_zero0(unsigned int* cntc, int ncb,
                        unsigned int* rowptr, int n, unsigned int e) {
    int i = blockIdx.x * blockDim.x + threadIdx.x;
    if (i < ncb) cntc[i] = 0u;
    if (i == 0) rowptr[n] = e;   // sentinel (also written by k_rowptr if covered)
}

__global__ void k_hist_c(const int* __restrict__ dst, int e, int ncb,
                         unsigned int* __restrict__ cntc) {
    __shared__ unsigned int h[NCB_MAX];
    for (int i = threadIdx.x; i < ncb; i += blockDim.x) h[i] = 0u;
    __syncthreads();
    int start = blockIdx.x * CHUNK;
    int end = min(start + CHUNK, e);
    int i = start + threadIdx.x;
    for (; i + 3 * 256 < end; i += 4 * 256) {
        unsigned d0 = dst[i], d1 = dst[i + 256], d2 = dst[i + 512], d3 = dst[i + 768];
        atomicAdd(&h[d0 >> CB_SHIFT], 1u);
        atomicAdd(&h[d1 >> CB_SHIFT], 1u);
        atomicAdd(&h[d2 >> CB_SHIFT], 1u);
        atomicAdd(&h[d3 >> CB_SHIFT], 1u);
    }
    for (; i < end; i += 256)
        atomicAdd(&h[((unsigned)dst[i]) >> CB_SHIFT], 1u);
    __syncthreads();
    for (int j = threadIdx.x; j < ncb; j += blockDim.x)
        if (h[j]) atomicAdd(&cntc[j], h[j]);
}

__global__ void k_scan(const unsigned int* __restrict__ cnt, int nb,
                       unsigned int* __restrict__ base,
                       unsigned int* __restrict__ cursor) {
    __shared__ unsigned int tsum[256];
    int t = threadIdx.x;
    int K = (nb + 255) / 256;
    unsigned int s = 0;
    for (int k = 0; k < K; k++) {
        int i = t * K + k;
        if (i < nb) s += cnt[i];
    }
    tsum[t] = s;
    __syncthreads();
    for (int off = 1; off < 256; off <<= 1) {
        unsigned int v = 0;
        if (t >= off) v = tsum[t - off];
        __syncthreads();
        if (t >= off) tsum[t] += v;
        __syncthreads();
    }
    unsigned int run = (t == 0) ? 0u : tsum[t - 1];
    for (int k = 0; k < K; k++) {
        int i = t * K + k;
        if (i < nb) { base[i] = run; cursor[i] = run; run += cnt[i]; }
    }
}

// records: (src << 10) | dst_local, bucketed by dst>>10
__global__ void k_fill_c(const int* __restrict__ src, const int* __restrict__ dst,
                         int e, int ncb, unsigned int* cursorc,
                         unsigned int* __restrict__ tmp) {
    __shared__ unsigned int h[NCB_MAX];
    __shared__ unsigned int lbase[NCB_MAX];
    for (int i = threadIdx.x; i < ncb; i += blockDim.x) h[i] = 0u;
    __syncthreads();
    int start = blockIdx.x * CHUNK;
    int end = min(start + CHUNK, e);
    int i = start + threadIdx.x;
    for (; i + 3 * 256 < end; i += 4 * 256) {
        unsigned d0 = dst[i], d1 = dst[i + 256], d2 = dst[i + 512], d3 = dst[i + 768];
        atomicAdd(&h[d0 >> CB_SHIFT], 1u);
        atomicAdd(&h[d1 >> CB_SHIFT], 1u);
        atomicAdd(&h[d2 >> CB_SHIFT], 1u);
        atomicAdd(&h[d3 >> CB_SHIFT], 1u);
    }
    for (; i < end; i += 256)
        atomicAdd(&h[((unsigned)dst[i]) >> CB_SHIFT], 1u);
    __syncthreads();
    for (int j = threadIdx.x; j < ncb; j += blockDim.x) {
        unsigned int c = h[j];
        lbase[j] = c ? atomicAdd(&cursorc[j], c) : 0u;
        h[j] = 0u;
    }
    __syncthreads();
    for (i = start + threadIdx.x; i < end; i += 256) {
        unsigned int d = (unsigned)dst[i];
        unsigned int b = d >> CB_SHIFT;
        unsigned int r = atomicAdd(&h[b], 1u);
        tmp[lbase[b] + r] = (((unsigned)src[i]) << CB_SHIFT) | (d & (CB - 1u));
    }
}

// per-slice per-node counts -> clsp[sl*n + node] (coalesced, no global atomics)
__global__ __launch_bounds__(BT) void
k_cls(const unsigned int* __restrict__ tmp,
      const unsigned int* __restrict__ basec,
      const unsigned int* __restrict__ cntc,
      unsigned int* __restrict__ clsp, int n) {
    __shared__ unsigned int degl[CB];
    int t = threadIdx.x;
    degl[t] = 0u;
    __syncthreads();
    int b = blockIdx.x / SPL, sl = blockIdx.x % SPL;
    unsigned int s = basec[b], m = cntc[b];
    for (unsigned int i = sl * BT + t; i < m; i += SPL * BT)
        atomicAdd(&degl[tmp[s + i] & (CB - 1u)], 1u);
    __syncthreads();
    int node = b * CB + t;
    if (node < n) clsp[(size_t)sl * n + node] = degl[t];
}

// per-bucket: deg = sum of slice counts, LDS scan -> global CSR rowptr,
// per-slice scatter starts (sstart), fused inv+xs4 build
__global__ __launch_bounds__(BT) void
k_rowptr(const unsigned int* __restrict__ clsp,
         const unsigned int* __restrict__ basec,
         const float* __restrict__ x,
         unsigned int* __restrict__ rowptr, unsigned int* __restrict__ sstart,
         float4* __restrict__ xs4, int n) {
    __shared__ unsigned int sc[BT];
    int t = threadIdx.x;
    int b = blockIdx.x;
    int node = b * CB + t;
    unsigned int c[SPL];
    unsigned int d = 0;
    if (node < n) {
#pragma unroll
        for (int sl = 0; sl < SPL; sl++) {
            c[sl] = clsp[(size_t)sl * n + node];
            d += c[sl];
        }
    } else {
#pragma unroll
        for (int sl = 0; sl < SPL; sl++) c[sl] = 0u;
    }
    sc[t] = d;
    __syncthreads();
    for (int off = 1; off < BT; off <<= 1) {
        unsigned int v = (t >= off) ? sc[t - off] : 0u;
        __syncthreads();
        sc[t] += v;
        __syncthreads();
    }
    unsigned int rp = basec[b] + sc[t] - d;   // exclusive prefix
    if (node <= n) rowptr[node] = rp;
    if (node < n) {
        unsigned int run = rp;
#pragma unroll
        for (int sl = 0; sl < SPL; sl++) {
            sstart[(size_t)sl * n + node] = run;
            run += c[sl];
        }
        float iv = rsqrtf((float)(1u + d));   // +1 self-loop
        xs4[node] = make_float4(x[3 * node] * iv, x[3 * node + 1] * iv,
                                x[3 * node + 2] * iv, iv);
    }
}

// scatter src ids into dst-sorted tmp2 (writes confined to 128KB bucket window)
__global__ __launch_bounds__(BT) void
k_sortB(const unsigned int* __restrict__ tmp,
        const unsigned int* __restrict__ basec,
        const unsigned int* __restrict__ cntc,
        const unsigned int* __restrict__ sstart,
        unsigned int* __restrict__ tmp2, int n) {
    __shared__ unsigned int cur[CB];
    int t = threadIdx.x;
    int b = blockIdx.x / SPL, sl = blockIdx.x % SPL;
    int node = b * CB + t;
    cur[t] = (node < n) ? sstart[(size_t)sl * n + node] : 0u;
    __syncthreads();
    unsigned int s = basec[b], m = cntc[b];
    for (unsigned int i = sl * BT + t; i < m; i += SPL * BT) {
        unsigned int rec = tmp[s + i];
        unsigned int r = atomicAdd(&cur[rec & (CB - 1u)], 1u);
        tmp2[r] = rec >> CB_SHIFT;
    }
}

// layer-1: one thread per node, atomic-free segment reduction over sorted srcs,
// fused epilogue (self-loop + W1 + b1 + relu + W2) -> t2s, out init
__global__ void k_s1(const unsigned int* __restrict__ rowptr,
                     const unsigned int* __restrict__ tmp2,
                     const float4* __restrict__ xs4,
                     const float* __restrict__ W1, const float* __restrict__ b1,
                     const float* __restrict__ W2, const float* __restrict__ b2,
                     float* __restrict__ t2s, float* __restrict__ out, int n) {
    int i = blockIdx.x * blockDim.x + threadIdx.x;
    if (i >= n) return;
    unsigned int s = rowptr[i], epos = rowptr[i + 1];
    float4 me = xs4[i];
    float v0 = me.x, v1 = me.y, v2 = me.z;   // self-loop contribution
    unsigned int j = s;
    for (; j + 4 <= epos; j += 4) {          // unroll-4: independent gathers
        unsigned a0 = tmp2[j], a1 = tmp2[j + 1], a2 = tmp2[j + 2], a3 = tmp2[j + 3];
        float4 p0 = xs4[a0], p1 = xs4[a1], p2 = xs4[a2], p3 = xs4[a3];
        v0 += (p0.x + p1.x) + (p2.x + p3.x);
        v1 += (p0.y + p1.y) + (p2.y + p3.y);
        v2 += (p0.z + p1.z) + (p2.z + p3.z);
    }
    for (; j < epos; j++) {
        float4 p = xs4[tmp2[j]];
        v0 += p.x; v1 += p.y; v2 += p.z;
    }
    float iv = me.w;
    v0 *= iv; v1 *= iv; v2 *= iv;
    float acc = 0.f;
#pragma unroll
    for (int k = 0; k < HIDDEN; k++) {
        float h = fmaxf(fmaf(v0, W1[k], fmaf(v1, W1[HIDDEN + k],
                       fmaf(v2, W1[2 * HIDDEN + k], b1[k]))), 0.f);
        acc += h * W2[k];
    }
    t2s[i] = acc * iv;                        // pre-scaled by inv
    out[i] = b2[0] + acc * iv * iv;           // bias + self-loop
}

// layer-2: one thread per node, scalar gathers of t2s
__global__ void k_s2(const unsigned int* __restrict__ rowptr,
                     const unsigned int* __restrict__ tmp2,
                     const float* __restrict__ t2s, const float4* __restrict__ xs4,
                     float* __restrict__ out, int n) {
    int i = blockIdx.x * blockDim.x + threadIdx.x;
    if (i >= n) return;
    unsigned int s = rowptr[i], epos = rowptr[i + 1];
    float v = 0.f, w = 0.f;
    unsigned int j = s;
    for (; j + 4 <= epos; j += 4) {
        unsigned a0 = tmp2[j], a1 = tmp2[j + 1], a2 = tmp2[j + 2], a3 = tmp2[j + 3];
        v += t2s[a0] + t2s[a1];
        w += t2s[a2] + t2s[a3];
    }
    for (; j < epos; j++) v += t2s[tmp2[j]];
    out[i] += (v + w) * xs4[i].w;
}

// ======================= split fallback (R7 path) =======================

__global__ void k_zero(unsigned int* a, int na, unsigned int* b, int nb) {
    int i = blockIdx.x * blockDim.x + threadIdx.x;
    if (i < na) a[i] = 0u;
    else if (i < na + nb) b[i - na] = 0u;
}
__global__ __launch_bounds__(BT) void
k_deg_split(const unsigned int* __restrict__ tmp, const unsigned int* __restrict__ basec,
            const unsigned int* __restrict__ cntc, unsigned int* __restrict__ deg, int n) {
    __shared__ unsigned int degl[CB];
    int t = threadIdx.x;
    degl[t] = 0u;
    __syncthreads();
    int b = blockIdx.x / SPL, sl = blockIdx.x % SPL;
    unsigned int s = basec[b], m = cntc[b];
    for (unsigned int i = sl * BT + t; i < m; i += SPL * BT)
        atomicAdd(&degl[tmp[s + i] & (CB - 1u)], 1u);
    __syncthreads();
    int node = b * CB + t;
    unsigned int c = degl[t];
    if (node < n && c) atomicAdd(&deg[node], c);
}
__global__ void k_inv_s(const unsigned int* __restrict__ deg, const float* __restrict__ x,
                        float4* __restrict__ xs4, int n) {
    int i = blockIdx.x * blockDim.x + threadIdx.x;
    if (i >= n) return;
    float iv = rsqrtf((float)(deg[i] + 1u));
    xs4[i] = make_float4(x[3 * i] * iv, x[3 * i + 1] * iv, x[3 * i + 2] * iv, iv);
}
__global__ __launch_bounds__(BT) void
k_s1_split(const unsigned int* __restrict__ tmp, const unsigned int* __restrict__ basec,
           const unsigned int* __restrict__ cntc, const float4* __restrict__ xs4,
           float* __restrict__ agg0, float* __restrict__ agg1, float* __restrict__ agg2, int n) {
    __shared__ float a0[CB], a1[CB], a2[CB];
    int t = threadIdx.x;
    a0[t] = 0.f; a1[t] = 0.f; a2[t] = 0.f;
    __syncthreads();
    int b = blockIdx.x / SPL, sl = blockIdx.x % SPL;
    unsigned int s = basec[b], m = cntc[b];
    for (unsigned int i = sl * BT + t; i < m; i += SPL * BT) {
        unsigned rec = tmp[s + i];
        float4 v = xs4[rec >> CB_SHIFT];
        unsigned dl = rec & (CB - 1u);
        atomicAdd(&a0[dl], v.x); atomicAdd(&a1[dl], v.y); atomicAdd(&a2[dl], v.z);
    }
    __syncthreads();
    int node = b * CB + t;
    if (node < n) {
        if (a0[t] != 0.f) atomicAdd(&agg0[node], a0[t]);
        if (a1[t] != 0.f) atomicAdd(&agg1[node], a1[t]);
        if (a2[t] != 0.f) atomicAdd(&agg2[node], a2[t]);
    }
}
__global__ void k_epi_s(const float* __restrict__ agg0, const float* __restrict__ agg1,
                        const float* __restrict__ agg2, const float4* __restrict__ xs4,
                        const float* __restrict__ W1, const float* __restrict__ b1,
                        const float* __restrict__ W2, const float* __restrict__ b2,
                        float* __restrict__ t2s, float* __restrict__ out, int n) {
    int i = blockIdx.x * blockDim.x + threadIdx.x;
    if (i >= n) return;
    float4 xv = xs4[i];
    float iv = xv.w;
    float v0 = iv * (agg0[i] + xv.x), v1 = iv * (agg1[i] + xv.y), v2 = iv * (agg2[i] + xv.z);
    float acc = 0.f;
#pragma unroll
    for (int j = 0; j < HIDDEN; j++) {
        float h = fmaxf(fmaf(v0, W1[j], fmaf(v1, W1[HIDDEN + j],
                       fmaf(v2, W1[2 * HIDDEN + j], b1[j]))), 0.f);
        acc += h * W2[j];
    }
    t2s[i] = acc * iv;
    out[i] = b2[0] + acc * iv * iv;
}
__global__ __launch_bounds__(BT) void
k_s2_split(const unsigned int* __restrict__ tmp, const unsigned int* __restrict__ basec,
           const unsigned int* __restrict__ cntc, const float* __restrict__ t2s,
           const float4* __restrict__ xs4, float* __restrict__ out, int n) {
    __shared__ float o[CB];
    int t = threadIdx.x;
    o[t] = 0.f;
    __syncthreads();
    int b = blockIdx.x / SPL, sl = blockIdx.x % SPL;
    unsigned int s = basec[b], m = cntc[b];
    for (unsigned int i = sl * BT + t; i < m; i += SPL * BT) {
        unsigned rec = tmp[s + i];
        atomicAdd(&o[rec & (CB - 1u)], t2s[rec >> CB_SHIFT]);
    }
    __syncthreads();
    int node = b * CB + t;
    if (node < n && o[t] != 0.f) atomicAdd(&out[node], o[t] * xs4[node].w);
}

// ======================= launch =======================

extern "C" void kernel_launch(void* const* d_in, const int* in_sizes, int n_in,
                              void* d_out, int out_size, void* d_ws, size_t ws_size,
                              hipStream_t stream) {
    const float* x  = (const float*)d_in[0];
    const int*   ei = (const int*)d_in[1];
    const float* W1 = (const float*)d_in[2];
    const float* b1 = (const float*)d_in[3];
    const float* W2 = (const float*)d_in[4];
    const float* b2 = (const float*)d_in[5];
    float* out = (float*)d_out;

    int n = in_sizes[0] / 3;
    int e = in_sizes[1] / 2;
    const int* src = ei;
    const int* dst = ei + e;
    const int B = 256;

    int ncb = (n + CB - 1) / CB;
    int gridE = (e + CHUNK - 1) / CHUNK;
    int gridN = (n + B - 1) / B;

    // CSR path ws: xs4[n] | t2s[n] | rowptr[n+1] | clsp[8n] | sstart[8n]
    //            | cntc/basec/cursorc[3*ncb] | tmp[e] | tmp2[e]
    size_t needcsr = (size_t)n * 16 + (size_t)n * 4 + (size_t)(n + 1) * 4
                   + (size_t)SPL * n * 8 + (size_t)ncb * 12 + (size_t)e * 8 + 64;
    size_t needsp = (size_t)n * 16 + (size_t)n * 16 + (size_t)n * 4
                  + (size_t)ncb * 12 + (size_t)e * 4;

    if (ncb <= NCB_MAX && n < (1 << 21) && ws_size >= needcsr) {
        float4* xs4 = (float4*)d_ws;                            // n
        float* t2s = (float*)(xs4 + n);                         // n
        unsigned int* rowptr = (unsigned int*)(t2s + n);        // n+1
        unsigned int* clsp   = rowptr + (n + 1);                // SPL*n
        unsigned int* sstart = clsp + (size_t)SPL * n;          // SPL*n
        unsigned int* cntc    = sstart + (size_t)SPL * n;       // ncb
        unsigned int* basec   = cntc + ncb;
        unsigned int* cursorc = basec + ncb;
        unsigned int* tmp     = cursorc + ncb;                  // e
        unsigned int* tmp2    = tmp + e;                        // e

        k_zero0<<<(ncb + B - 1) / B, B, 0, stream>>>(cntc, ncb, rowptr, n, (unsigned)e);
        k_hist_c<<<gridE, B, 0, stream>>>(dst, e, ncb, cntc);
        k_scan<<<1, B, 0, stream>>>(cntc, ncb, basec, cursorc);
        k_fill_c<<<gridE, B, 0, stream>>>(src, dst, e, ncb, cursorc, tmp);
        k_cls<<<ncb * SPL, BT, 0, stream>>>(tmp, basec, cntc, clsp, n);
        k_rowptr<<<ncb, BT, 0, stream>>>(clsp, basec, x, rowptr, sstart, xs4, n);
        k_sortB<<<ncb * SPL, BT, 0, stream>>>(tmp, basec, cntc, sstart, tmp2, n);
        k_s1<<<gridN, B, 0, stream>>>(rowptr, tmp2, xs4, W1, b1, W2, b2, t2s, out, n);
        k_s2<<<gridN, B, 0, stream>>>(rowptr, tmp2, t2s, xs4, out, n);
    } else if (ncb <= NCB_MAX && n < (1 << 22) && ws_size >= needsp) {
        float4* xs4 = (float4*)d_ws;
        float* agg0 = (float*)(xs4 + n);
        float* agg1 = agg0 + n;
        float* agg2 = agg1 + n;
        unsigned int* deg = (unsigned int*)(agg2 + n);
        float* t2s = (float*)(deg + n);
        unsigned int* cntc    = (unsigned int*)(t2s + n);
        unsigned int* basec   = cntc + ncb;
        unsigned int* cursorc = basec + ncb;
        unsigned int* tmp     = cursorc + ncb;

        k_zero<<<(4 * n + ncb + B - 1) / B, B, 0, stream>>>((unsigned int*)agg0, 4 * n, cntc, ncb);
        k_hist_c<<<gridE, B, 0, stream>>>(dst, e, ncb, cntc);
        k_scan<<<1, B, 0, stream>>>(cntc, ncb, basec, cursorc);
        k_fill_c<<<gridE, B, 0, stream>>>(src, dst, e, ncb, cursorc, tmp);
        k_deg_split<<<ncb * SPL, BT, 0, stream>>>(tmp, basec, cntc, deg, n);
        k_inv_s<<<gridN, B, 0, stream>>>(deg, x, xs4, n);
        k_s1_split<<<ncb * SPL, BT, 0, stream>>>(tmp, basec, cntc, xs4, agg0, agg1, agg2, n);
        k_epi_s<<<gridN, B, 0, stream>>>(agg0, agg1, agg2, xs4, W1, b1, W2, b2, t2s, out, n);
        k_s2_split<<<ncb * SPL, BT, 0, stream>>>(tmp, basec, cntc, t2s, xs4, out, n);
    }
}

// Round 10
// 207.768 us; speedup vs baseline: 1.4199x; 1.0254x over previous
//
#include <hip/hip_runtime.h>

#define HIDDEN 16
#define CB 1024         // nodes per coarse bucket (power of two)
#define CB_SHIFT 10
#define NCB_MAX 512     // max coarse buckets
#define CHUNK 4096      // edges per block in hist/fill passes
#define SPL 16          // slice-blocks per bucket in count/scatter kernels
#define BT 1024         // threads per sliced block

// ======================= sorted-CSR path =======================

__global__ void k_zero0(unsigned int* cntc, int ncb,
                        unsigned int* rowptr, int n, unsigned int e) {
    int i = blockIdx.x * blockDim.x + threadIdx.x;
    if (i < ncb) cntc[i] = 0u;
    if (i == 0) rowptr[n] = e;   // sentinel
}

// per-chunk bucket histogram -> hcT[b*nchunk + chunk] (transposed) + totals
__global__ void k_hist_c(const int* __restrict__ dst, int e, int ncb, int nchunk,
                         unsigned int* __restrict__ cntc,
                         unsigned int* __restrict__ hcT) {
    __shared__ unsigned int h[NCB_MAX];
    for (int i = threadIdx.x; i < ncb; i += blockDim.x) h[i] = 0u;
    __syncthreads();
    int start = blockIdx.x * CHUNK;
    int end = min(start + CHUNK, e);
    int i = start + threadIdx.x;
    for (; i + 3 * 256 < end; i += 4 * 256) {
        unsigned d0 = dst[i], d1 = dst[i + 256], d2 = dst[i + 512], d3 = dst[i + 768];
        atomicAdd(&h[d0 >> CB_SHIFT], 1u);
        atomicAdd(&h[d1 >> CB_SHIFT], 1u);
        atomicAdd(&h[d2 >> CB_SHIFT], 1u);
        atomicAdd(&h[d3 >> CB_SHIFT], 1u);
    }
    for (; i < end; i += 256)
        atomicAdd(&h[((unsigned)dst[i]) >> CB_SHIFT], 1u);
    __syncthreads();
    for (int j = threadIdx.x; j < ncb; j += blockDim.x) {
        hcT[(size_t)j * nchunk + blockIdx.x] = h[j];
        if (h[j]) atomicAdd(&cntc[j], h[j]);
    }
}

// exclusive scan of bucket totals -> basec
__global__ void k_scan(const unsigned int* __restrict__ cnt, int nb,
                       unsigned int* __restrict__ base) {
    __shared__ unsigned int tsum[256];
    int t = threadIdx.x;
    int K = (nb + 255) / 256;
    unsigned int s = 0;
    for (int k = 0; k < K; k++) {
        int i = t * K + k;
        if (i < nb) s += cnt[i];
    }
    tsum[t] = s;
    __syncthreads();
    for (int off = 1; off < 256; off <<= 1) {
        unsigned int v = 0;
        if (t >= off) v = tsum[t - off];
        __syncthreads();
        if (t >= off) tsum[t] += v;
        __syncthreads();
    }
    unsigned int run = (t == 0) ? 0u : tsum[t - 1];
    for (int k = 0; k < K; k++) {
        int i = t * K + k;
        if (i < nb) { base[i] = run; run += cnt[i]; }
    }
}

// per-bucket scan over chunks: lbasec[b*nchunk + c] = basec[b] + prefix(hcT)
__global__ void k_scanc(const unsigned int* __restrict__ hcT,
                        const unsigned int* __restrict__ basec,
                        unsigned int* __restrict__ lbasec, int nchunk) {
    __shared__ unsigned int ts[256];
    __shared__ unsigned int carry;
    int b = blockIdx.x, t = threadIdx.x;
    if (t == 0) carry = basec[b];
    __syncthreads();
    for (int t0 = 0; t0 < nchunk; t0 += 256) {
        int i = t0 + t;
        unsigned int v = (i < nchunk) ? hcT[(size_t)b * nchunk + i] : 0u;
        ts[t] = v;
        __syncthreads();
        for (int off = 1; off < 256; off <<= 1) {
            unsigned int u = (t >= off) ? ts[t - off] : 0u;
            __syncthreads();
            ts[t] += u;
            __syncthreads();
        }
        if (i < nchunk) lbasec[(size_t)b * nchunk + i] = carry + ts[t] - v;
        __syncthreads();
        if (t == 0) carry += ts[255];
        __syncthreads();
    }
}

// scatter records (src<<10 | dst_local) using precomputed per-chunk bases:
// no histogram pass, no cursor atomics
__global__ void k_fill_c(const int* __restrict__ src, const int* __restrict__ dst,
                         int e, int ncb, int nchunk,
                         const unsigned int* __restrict__ lbasec,
                         unsigned int* __restrict__ tmp) {
    __shared__ unsigned int h[NCB_MAX];
    __shared__ unsigned int lb[NCB_MAX];
    for (int j = threadIdx.x; j < ncb; j += blockDim.x) {
        lb[j] = lbasec[(size_t)j * nchunk + blockIdx.x];
        h[j] = 0u;
    }
    __syncthreads();
    int start = blockIdx.x * CHUNK;
    int end = min(start + CHUNK, e);
    for (int i = start + threadIdx.x; i < end; i += 256) {
        unsigned int d = (unsigned)dst[i];
        unsigned int s = (unsigned)src[i];
        unsigned int b = d >> CB_SHIFT;
        unsigned int r = atomicAdd(&h[b], 1u);
        tmp[lb[b] + r] = (s << CB_SHIFT) | (d & (CB - 1u));
    }
}

// per-slice per-node counts -> clsp[sl*n + node]
__global__ __launch_bounds__(BT) void
k_cls(const unsigned int* __restrict__ tmp,
      const unsigned int* __restrict__ basec,
      const unsigned int* __restrict__ cntc,
      unsigned int* __restrict__ clsp, int n) {
    __shared__ unsigned int degl[CB];
    int t = threadIdx.x;
    degl[t] = 0u;
    __syncthreads();
    int b = blockIdx.x / SPL, sl = blockIdx.x % SPL;
    unsigned int s = basec[b], m = cntc[b];
    for (unsigned int i = sl * BT + t; i < m; i += SPL * BT)
        atomicAdd(&degl[tmp[s + i] & (CB - 1u)], 1u);
    __syncthreads();
    int node = b * CB + t;
    if (node < n) clsp[(size_t)sl * n + node] = degl[t];
}

// per-bucket: deg, LDS scan -> rowptr, per-slice starts, fused inv+xs4 build
__global__ __launch_bounds__(BT) void
k_rowptr(const unsigned int* __restrict__ clsp,
         const unsigned int* __restrict__ basec,
         const float* __restrict__ x,
         unsigned int* __restrict__ rowptr, unsigned int* __restrict__ sstart,
         float4* __restrict__ xs4, int n) {
    __shared__ unsigned int sc[BT];
    int t = threadIdx.x;
    int b = blockIdx.x;
    int node = b * CB + t;
    unsigned int c[SPL];
    unsigned int d = 0;
    if (node < n) {
#pragma unroll
        for (int sl = 0; sl < SPL; sl++) {
            c[sl] = clsp[(size_t)sl * n + node];
            d += c[sl];
        }
    } else {
#pragma unroll
        for (int sl = 0; sl < SPL; sl++) c[sl] = 0u;
    }
    sc[t] = d;
    __syncthreads();
    for (int off = 1; off < BT; off <<= 1) {
        unsigned int v = (t >= off) ? sc[t - off] : 0u;
        __syncthreads();
        sc[t] += v;
        __syncthreads();
    }
    unsigned int rp = basec[b] + sc[t] - d;
    if (node <= n) rowptr[node] = rp;
    if (node < n) {
        unsigned int run = rp;
#pragma unroll
        for (int sl = 0; sl < SPL; sl++) {
            sstart[(size_t)sl * n + node] = run;
            run += c[sl];
        }
        float iv = rsqrtf((float)(1u + d));
        xs4[node] = make_float4(x[3 * node] * iv, x[3 * node + 1] * iv,
                                x[3 * node + 2] * iv, iv);
    }
}

// scatter src ids into dst-sorted tmp2
__global__ __launch_bounds__(BT) void
k_sortB(const unsigned int* __restrict__ tmp,
        const unsigned int* __restrict__ basec,
        const unsigned int* __restrict__ cntc,
        const unsigned int* __restrict__ sstart,
        unsigned int* __restrict__ tmp2, int n) {
    __shared__ unsigned int cur[CB];
    int t = threadIdx.x;
    int b = blockIdx.x / SPL, sl = blockIdx.x % SPL;
    int node = b * CB + t;
    cur[t] = (node < n) ? sstart[(size_t)sl * n + node] : 0u;
    __syncthreads();
    unsigned int s = basec[b], m = cntc[b];
    for (unsigned int i = sl * BT + t; i < m; i += SPL * BT) {
        unsigned int rec = tmp[s + i];
        unsigned int r = atomicAdd(&cur[rec & (CB - 1u)], 1u);
        tmp2[r] = rec >> CB_SHIFT;
    }
}

// layer-1: one thread per node, atomic-free segment reduction, fused epilogue
__global__ void k_s1(const unsigned int* __restrict__ rowptr,
                     const unsigned int* __restrict__ tmp2,
                     const float4* __restrict__ xs4,
                     const float* __restrict__ W1, const float* __restrict__ b1,
                     const float* __restrict__ W2, const float* __restrict__ b2,
                     float* __restrict__ t2s, float* __restrict__ out, int n) {
    int i = blockIdx.x * blockDim.x + threadIdx.x;
    if (i >= n) return;
    unsigned int s = rowptr[i], epos = rowptr[i + 1];
    float4 me = xs4[i];
    float v0 = me.x, v1 = me.y, v2 = me.z;   // self-loop
    unsigned int j = s;
    for (; j + 8 <= epos; j += 8) {          // unroll-8: independent gathers
        unsigned a[8];
#pragma unroll
        for (int k = 0; k < 8; k++) a[k] = tmp2[j + k];
        float4 p[8];
#pragma unroll
        for (int k = 0; k < 8; k++) p[k] = xs4[a[k]];
#pragma unroll
        for (int k = 0; k < 8; k++) { v0 += p[k].x; v1 += p[k].y; v2 += p[k].z; }
    }
    for (; j < epos; j++) {
        float4 p = xs4[tmp2[j]];
        v0 += p.x; v1 += p.y; v2 += p.z;
    }
    float iv = me.w;
    v0 *= iv; v1 *= iv; v2 *= iv;
    float acc = 0.f;
#pragma unroll
    for (int k = 0; k < HIDDEN; k++) {
        float h = fmaxf(fmaf(v0, W1[k], fmaf(v1, W1[HIDDEN + k],
                       fmaf(v2, W1[2 * HIDDEN + k], b1[k]))), 0.f);
        acc += h * W2[k];
    }
    t2s[i] = acc * iv;
    out[i] = b2[0] + acc * iv * iv;
}

// layer-2: one thread per node, scalar gathers of t2s
__global__ void k_s2(const unsigned int* __restrict__ rowptr,
                     const unsigned int* __restrict__ tmp2,
                     const float* __restrict__ t2s, const float4* __restrict__ xs4,
                     float* __restrict__ out, int n) {
    int i = blockIdx.x * blockDim.x + threadIdx.x;
    if (i >= n) return;
    unsigned int s = rowptr[i], epos = rowptr[i + 1];
    float v = 0.f;
    unsigned int j = s;
    for (; j + 8 <= epos; j += 8) {
        unsigned a[8];
#pragma unroll
        for (int k = 0; k < 8; k++) a[k] = tmp2[j + k];
        float p[8];
#pragma unroll
        for (int k = 0; k < 8; k++) p[k] = t2s[a[k]];
        v += ((p[0] + p[1]) + (p[2] + p[3])) + ((p[4] + p[5]) + (p[6] + p[7]));
    }
    for (; j < epos; j++) v += t2s[tmp2[j]];
    out[i] += v * xs4[i].w;
}

// ======================= split fallback backend =======================

__global__ void k_zero(unsigned int* a, int na) {
    int i = blockIdx.x * blockDim.x + threadIdx.x;
    if (i < na) a[i] = 0u;
}
__global__ __launch_bounds__(BT) void
k_deg_split(const unsigned int* __restrict__ tmp, const unsigned int* __restrict__ basec,
            const unsigned int* __restrict__ cntc, unsigned int* __restrict__ deg, int n) {
    __shared__ unsigned int degl[CB];
    int t = threadIdx.x;
    degl[t] = 0u;
    __syncthreads();
    int b = blockIdx.x / SPL, sl = blockIdx.x % SPL;
    unsigned int s = basec[b], m = cntc[b];
    for (unsigned int i = sl * BT + t; i < m; i += SPL * BT)
        atomicAdd(&degl[tmp[s + i] & (CB - 1u)], 1u);
    __syncthreads();
    int node = b * CB + t;
    unsigned int c = degl[t];
    if (node < n && c) atomicAdd(&deg[node], c);
}
__global__ void k_inv_s(const unsigned int* __restrict__ deg, const float* __restrict__ x,
                        float4* __restrict__ xs4, int n) {
    int i = blockIdx.x * blockDim.x + threadIdx.x;
    if (i >= n) return;
    float iv = rsqrtf((float)(deg[i] + 1u));
    xs4[i] = make_float4(x[3 * i] * iv, x[3 * i + 1] * iv, x[3 * i + 2] * iv, iv);
}
__global__ __launch_bounds__(BT) void
k_s1_split(const unsigned int* __restrict__ tmp, const unsigned int* __restrict__ basec,
           const unsigned int* __restrict__ cntc, const float4* __restrict__ xs4,
           float* __restrict__ agg0, float* __restrict__ agg1, float* __restrict__ agg2, int n) {
    __shared__ float a0[CB], a1[CB], a2[CB];
    int t = threadIdx.x;
    a0[t] = 0.f; a1[t] = 0.f; a2[t] = 0.f;
    __syncthreads();
    int b = blockIdx.x / SPL, sl = blockIdx.x % SPL;
    unsigned int s = basec[b], m = cntc[b];
    for (unsigned int i = sl * BT + t; i < m; i += SPL * BT) {
        unsigned rec = tmp[s + i];
        float4 v = xs4[rec >> CB_SHIFT];
        unsigned dl = rec & (CB - 1u);
        atomicAdd(&a0[dl], v.x); atomicAdd(&a1[dl], v.y); atomicAdd(&a2[dl], v.z);
    }
    __syncthreads();
    int node = b * CB + t;
    if (node < n) {
        if (a0[t] != 0.f) atomicAdd(&agg0[node], a0[t]);
        if (a1[t] != 0.f) atomicAdd(&agg1[node], a1[t]);
        if (a2[t] != 0.f) atomicAdd(&agg2[node], a2[t]);
    }
}
__global__ void k_epi_s(const float* __restrict__ agg0, const float* __restrict__ agg1,
                        const float* __restrict__ agg2, const float4* __restrict__ xs4,
                        const float* __restrict__ W1, const float* __restrict__ b1,
                        const float* __restrict__ W2, const float* __restrict__ b2,
                        float* __restrict__ t2s, float* __restrict__ out, int n) {
    int i = blockIdx.x * blockDim.x + threadIdx.x;
    if (i >= n) return;
    float4 xv = xs4[i];
    float iv = xv.w;
    float v0 = iv * (agg0[i] + xv.x), v1 = iv * (agg1[i] + xv.y), v2 = iv * (agg2[i] + xv.z);
    float acc = 0.f;
#pragma unroll
    for (int j = 0; j < HIDDEN; j++) {
        float h = fmaxf(fmaf(v0, W1[j], fmaf(v1, W1[HIDDEN + j],
                       fmaf(v2, W1[2 * HIDDEN + j], b1[j]))), 0.f);
        acc += h * W2[j];
    }
    t2s[i] = acc * iv;
    out[i] = b2[0] + acc * iv * iv;
}
__global__ __launch_bounds__(BT) void
k_s2_split(const unsigned int* __restrict__ tmp, const unsigned int* __restrict__ basec,
           const unsigned int* __restrict__ cntc, const float* __restrict__ t2s,
           const float4* __restrict__ xs4, float* __restrict__ out, int n) {
    __shared__ float o[CB];
    int t = threadIdx.x;
    o[t] = 0.f;
    __syncthreads();
    int b = blockIdx.x / SPL, sl = blockIdx.x % SPL;
    unsigned int s = basec[b], m = cntc[b];
    for (unsigned int i = sl * BT + t; i < m; i += SPL * BT) {
        unsigned rec = tmp[s + i];
        atomicAdd(&o[rec & (CB - 1u)], t2s[rec >> CB_SHIFT]);
    }
    __syncthreads();
    int node = b * CB + t;
    if (node < n && o[t] != 0.f) atomicAdd(&out[node], o[t] * xs4[node].w);
}

// ======================= launch =======================

extern "C" void kernel_launch(void* const* d_in, const int* in_sizes, int n_in,
                              void* d_out, int out_size, void* d_ws, size_t ws_size,
                              hipStream_t stream) {
    const float* x  = (const float*)d_in[0];
    const int*   ei = (const int*)d_in[1];
    const float* W1 = (const float*)d_in[2];
    const float* b1 = (const float*)d_in[3];
    const float* W2 = (const float*)d_in[4];
    const float* b2 = (const float*)d_in[5];
    float* out = (float*)d_out;

    int n = in_sizes[0] / 3;
    int e = in_sizes[1] / 2;
    const int* src = ei;
    const int* dst = ei + e;
    const int B = 256;

    int ncb = (n + CB - 1) / CB;
    int gridE = (e + CHUNK - 1) / CHUNK;
    int gridN = (n + B - 1) / B;

    // CSR ws: xs4[n] | t2s[n] | rowptr[n+1] | clsp[SPL*n] | sstart[SPL*n]
    //       | cntc/basec[2*ncb] | hcT[ncb*gridE] | lbasec[ncb*gridE] | tmp[e] | tmp2[e]
    size_t needcsr = (size_t)n * 16 + (size_t)n * 4 + (size_t)(n + 1) * 4
                   + (size_t)SPL * n * 8 + (size_t)ncb * 8
                   + (size_t)ncb * gridE * 8 + (size_t)e * 8 + 64;
    size_t needsp = (size_t)n * 16 + (size_t)n * 16 + (size_t)n * 4
                  + (size_t)ncb * 8 + (size_t)ncb * gridE * 8 + (size_t)e * 4;

    if (ncb <= NCB_MAX && n < (1 << 21) && ws_size >= needcsr) {
        float4* xs4 = (float4*)d_ws;                            // n
        float* t2s = (float*)(xs4 + n);                         // n
        unsigned int* rowptr = (unsigned int*)(t2s + n);        // n+1
        unsigned int* clsp   = rowptr + (n + 1);                // SPL*n
        unsigned int* sstart = clsp + (size_t)SPL * n;          // SPL*n
        unsigned int* cntc   = sstart + (size_t)SPL * n;        // ncb
        unsigned int* basec  = cntc + ncb;                      // ncb
        unsigned int* hcT    = basec + ncb;                     // ncb*gridE
        unsigned int* lbasec = hcT + (size_t)ncb * gridE;       // ncb*gridE
        unsigned int* tmp    = lbasec + (size_t)ncb * gridE;    // e
        unsigned int* tmp2   = tmp + e;                         // e

        k_zero0<<<(ncb + B - 1) / B, B, 0, stream>>>(cntc, ncb, rowptr, n, (unsigned)e);
        k_hist_c<<<gridE, B, 0, stream>>>(dst, e, ncb, gridE, cntc, hcT);
        k_scan<<<1, B, 0, stream>>>(cntc, ncb, basec);
        k_scanc<<<ncb, B, 0, stream>>>(hcT, basec, lbasec, gridE);
        k_fill_c<<<gridE, B, 0, stream>>>(src, dst, e, ncb, gridE, lbasec, tmp);
        k_cls<<<ncb * SPL, BT, 0, stream>>>(tmp, basec, cntc, clsp, n);
        k_rowptr<<<ncb, BT, 0, stream>>>(clsp, basec, x, rowptr, sstart, xs4, n);
        k_sortB<<<ncb * SPL, BT, 0, stream>>>(tmp, basec, cntc, sstart, tmp2, n);
        k_s1<<<gridN, B, 0, stream>>>(rowptr, tmp2, xs4, W1, b1, W2, b2, t2s, out, n);
        k_s2<<<gridN, B, 0, stream>>>(rowptr, tmp2, t2s, xs4, out, n);
    } else if (ncb <= NCB_MAX && n < (1 << 22) && ws_size >= needsp) {
        float4* xs4 = (float4*)d_ws;
        float* agg0 = (float*)(xs4 + n);
        float* agg1 = agg0 + n;
        float* agg2 = agg1 + n;
        unsigned int* deg = (unsigned int*)(agg2 + n);
        float* t2s = (float*)(deg + n);
        unsigned int* cntc   = (unsigned int*)(t2s + n);
        unsigned int* basec  = cntc + ncb;
        unsigned int* hcT    = basec + ncb;
        unsigned int* lbasec = hcT + (size_t)ncb * gridE;
        unsigned int* tmp    = lbasec + (size_t)ncb * gridE;

        k_zero<<<(4 * n + ncb + B - 1) / B, B, 0, stream>>>((unsigned int*)agg0, 4 * n);
        k_zero<<<(ncb + B - 1) / B, B, 0, stream>>>(cntc, ncb);
        k_hist_c<<<gridE, B, 0, stream>>>(dst, e, ncb, gridE, cntc, hcT);
        k_scan<<<1, B, 0, stream>>>(cntc, ncb, basec);
        k_scanc<<<ncb, B, 0, stream>>>(hcT, basec, lbasec, gridE);
        k_fill_c<<<gridE, B, 0, stream>>>(src, dst, e, ncb, gridE, lbasec, tmp);
        k_deg_split<<<ncb * SPL, BT, 0, stream>>>(tmp, basec, cntc, deg, n);
        k_inv_s<<<gridN, B, 0, stream>>>(deg, x, xs4, n);
        k_s1_split<<<ncb * SPL, BT, 0, stream>>>(tmp, basec, cntc, xs4, agg0, agg1, agg2, n);
        k_epi_s<<<gridN, B, 0, stream>>>(agg0, agg1, agg2, xs4, W1, b1, W2, b2, t2s, out, n);
        k_s2_split<<<ncb * SPL, BT, 0, stream>>>(tmp, basec, cntc, t2s, xs4, out, n);
    }
}